// Round 1
// baseline (1048.422 us; speedup 1.0000x reference)
//
#include <hip/hip_runtime.h>

// GCN neighbor-topk aggregation, N=50000, M=32, D=128, K=8.
// Outputs (concat, float32): aggregate [N,128] then selected_ids [N,8] (as float).
// Memory-bound: src_info stream = 819 MB dominates; target ~145 us @ 6.3 TB/s.

#define NROWS 50000
#define M 32
#define D 128
#define K 8
#define RPB 8            // rows per block (256 threads / 32 threads-per-row)

__global__ __launch_bounds__(256) void gcn_kernel(
    const float* __restrict__ interact,     // [N, M]
    const float* __restrict__ initial,      // [N, M]
    const float4* __restrict__ srcinfo4,    // [N, M, D/4]
    const float4* __restrict__ buffer4,     // [N, D/4]
    const float* __restrict__ keep_rate_p,  // [1]
    const int* __restrict__ source_id,      // [N, M] (int64 narrowed to int32 by harness)
    float4* __restrict__ out_agg4,          // [N, D/4]
    float* __restrict__ out_ids)            // [N, K]
{
    __shared__ float s_score[RPB][M];
    __shared__ float s_padj[RPB][M];

    const int tid = threadIdx.x;
    const int r   = tid >> 5;            // row slot within block
    const int m   = tid & 31;            // neighbor index / dim-group index
    const int row = blockIdx.x * RPB + r;
    const float keep = keep_rate_p[0];

    float s = -1e30f, ini = 0.0f;
    int sid = 0;
    if (row < NROWS) {
        s   = interact[row * M + m];
        ini = initial[row * M + m];
        sid = source_id[row * M + m];
    }
    s_score[r][m] = s;
    __syncthreads();

    // rank = #{j: s_j > s_m} + #{j<m: s_j == s_m}  -> matches jax.lax.top_k
    // (descending values, ties broken by lower index first).
    int rank = 0;
    #pragma unroll
    for (int j = 0; j < M; ++j) {
        float sj = s_score[r][j];
        rank += (sj > s) | ((sj == s) & (j < m));
    }

    // pseudo_adj: sigmoid(score - (1-mask)*1e11); masked-out entries underflow
    // to exactly 0, so compute directly.
    float sig  = 1.0f / (1.0f + expf(-s));
    float padj = (1.0f - keep) * ((rank < K) ? sig : 0.0f) + keep * ini;
    s_padj[r][m] = padj;

    // coefficient = sum_m padj + 1, 32-lane butterfly (lanes 0-31 / 32-63 are
    // distinct rows within the wave64).
    float sum = padj;
    #pragma unroll
    for (int off = 16; off >= 1; off >>= 1)
        sum += __shfl_xor(sum, off, 32);
    const float inv_coeff = 1.0f / (sum + 1.0f);

    if (row < NROWS && rank < K) {
        out_ids[row * K + rank] = (float)sid;   // ids < 2^24: exact in fp32
    }
    __syncthreads();

    if (row < NROWS) {
        // Each thread owns dims [4m, 4m+3]; per mm the 32 row-threads read one
        // contiguous 512B segment (16B/lane) -> fully coalesced.
        const float4* src = srcinfo4 + (size_t)row * (M * (D / 4)) + m;
        float4 acc = make_float4(0.f, 0.f, 0.f, 0.f);
        #pragma unroll 8
        for (int mm = 0; mm < M; ++mm) {
            const float w = s_padj[r][mm];      // row-broadcast LDS read (free)
            const float4 v = src[mm * (D / 4)];
            acc.x += w * v.x;
            acc.y += w * v.y;
            acc.z += w * v.z;
            acc.w += w * v.w;
        }
        const float4 b = buffer4[(size_t)row * (D / 4) + m];
        float4 o;
        o.x = (acc.x + b.x) * inv_coeff;
        o.y = (acc.y + b.y) * inv_coeff;
        o.z = (acc.z + b.z) * inv_coeff;
        o.w = (acc.w + b.w) * inv_coeff;
        out_agg4[(size_t)row * (D / 4) + m] = o;
    }
}

extern "C" void kernel_launch(void* const* d_in, const int* in_sizes, int n_in,
                              void* d_out, int out_size, void* d_ws, size_t ws_size,
                              hipStream_t stream) {
    const float*  interact  = (const float*)d_in[0];
    const float*  initial   = (const float*)d_in[1];
    const float4* srcinfo4  = (const float4*)d_in[2];
    const float4* buffer4   = (const float4*)d_in[3];
    // d_in[4] = W : dead code in the reference (relu(fc(.)) is discarded)
    const float*  keep_rate = (const float*)d_in[5];
    const int*    source_id = (const int*)d_in[6];

    float* out_agg = (float*)d_out;                       // [N, D]
    float* out_ids = (float*)d_out + (size_t)NROWS * D;   // [N, K]

    const int blocks = (NROWS + RPB - 1) / RPB;           // 6250
    gcn_kernel<<<blocks, 256, 0, stream>>>(
        interact, initial, srcinfo4, buffer4, keep_rate, source_id,
        (float4*)out_agg, out_ids);
}